// Round 10
// baseline (1269.326 us; speedup 1.0000x reference)
//
#include <hip/hip_runtime.h>
#include <hip/hip_bf16.h>
#include <stdint.h>

typedef __attribute__((ext_vector_type(8))) __bf16 bf16x8;
typedef __attribute__((ext_vector_type(4))) float f32x4;

#define IN_F   4096
#define OUT_F  4096
#define M_ROWS 16384   // 8 * 2048

static __device__ __forceinline__ unsigned short f2bf(float f) {
    unsigned int u = __float_as_uint(f);
    u += 0x7FFFu + ((u >> 16) & 1u);   // round-to-nearest-even
    return (unsigned short)(u >> 16);
}

// ---------------------------------------------------------------------------
// Kernel 1: fused prep (build bf16 weight; convert x to bf16).
// ---------------------------------------------------------------------------
#define PREP_WBLK 1366
#define PREP_NBLK 4096

__global__ __launch_bounds__(256) void prep_kernel(
    const float* __restrict__ weight, const float* __restrict__ leafs,
    const float* __restrict__ x,
    unsigned short* __restrict__ wb, unsigned short* __restrict__ xbuf)
{
    const int t = threadIdx.x;
    if (blockIdx.x < PREP_WBLK) {
        __shared__ float s[4][8][8];
        {
            const int o = t >> 6, a = (t >> 3) & 7, b = t & 7;
            float acc = 0.f;
            #pragma unroll
            for (int r = 0; r < 8; ++r)
                acc += leafs[o * 512 + r * 64 + a * 8 + b];
            s[o][a][b] = acc;
        }
        __syncthreads();

        const int total = (OUT_F * IN_F) / 8;
        for (int idx = blockIdx.x * 256 + t; idx < total; idx += PREP_WBLK * 256) {
            const int n  = idx >> 9;
            const int kg = idx & 511;
            const int n0 = n >> 9, n1 = (n >> 6) & 7, n2 = (n >> 3) & 7, n3 = n & 7;
            const int k0 = kg >> 6, k1 = (kg >> 3) & 7, k2 = kg & 7;
            const float p = s[0][k0][n0] * s[1][k1][n1] * s[2][k2][n2];
            const float4* wp = (const float4*)(weight + (size_t)n * IN_F + kg * 8);
            const float4 w0 = wp[0], w1 = wp[1];
            const float wv[8] = {w0.x, w0.y, w0.z, w0.w, w1.x, w1.y, w1.z, w1.w};
            unsigned int pk[4];
            #pragma unroll
            for (int j = 0; j < 4; ++j) {
                unsigned int lo = f2bf(wv[2*j]   + p * s[3][2*j]  [n3]);
                unsigned int hi = f2bf(wv[2*j+1] + p * s[3][2*j+1][n3]);
                pk[j] = lo | (hi << 16);
            }
            *reinterpret_cast<uint4*>(wb + (size_t)n * IN_F + kg * 8) =
                make_uint4(pk[0], pk[1], pk[2], pk[3]);
        }
    } else {
        const long long n8 = (long long)M_ROWS * IN_F / 8;
        const int xblocks = PREP_NBLK - PREP_WBLK;
        for (long long idx = (long long)(blockIdx.x - PREP_WBLK) * 256 + t;
             idx < n8; idx += (long long)xblocks * 256) {
            const float4* xp = (const float4*)(x + idx * 8);
            const float4 a = xp[0], b = xp[1];
            const float v[8] = {a.x, a.y, a.z, a.w, b.x, b.y, b.z, b.w};
            unsigned int pk[4];
            #pragma unroll
            for (int j = 0; j < 4; ++j)
                pk[j] = (unsigned int)f2bf(v[2*j]) | ((unsigned int)f2bf(v[2*j+1]) << 16);
            *reinterpret_cast<uint4*>(xbuf + idx * 8) =
                make_uint4(pk[0], pk[1], pk[2], pk[3]);
        }
    }
}

// ---------------------------------------------------------------------------
// Kernel 2: 256x256 GEMM, 16x16x32 MFMA, A DIRECT-FROM-GLOBAL (flatmm style).
//
// Rationale (R1-R9 evidence): per-CU time has been additive MFMA+LDS across
// all schedule/occupancy variants -> the LDS pipe is the contended resource.
// A was 8 of 12 b128 reads per wave-half; moving A to global (L2-hot: each
// XCD re-reads its 2MB A slice 16x) cuts the LDS pipe to 1/3, leaving MFMA
// (2483 cyc per CU-tile) as the sole critical pipe.
//
// B in LDS exactly as R3 (0 conflicts measured): panels [2buf][2kk][256][64B]
// at ldsb, element (row,col) at byte row*64 + ((col*2) ^ ((row&6)<<3)),
// staged via global_load_lds from inverse-swizzled sources. 64 KiB total.
//
// A registers: aC (current half's 8 frags), aN (next half's), alternating;
// loads use uniform base xbh (advances 64 elems/tile) + per-lane 32-bit aoff.
//
// Per tile t (buf P), FIFO-verified waits (steady state entering: [aC8]):
//   1. STAGE_B(P^1, t+1): G4          FIFO [aC8,G4]
//   2. load aN <- A(t,kk1)            FIFO [aC8,G4,aN8] = 20
//   3. ds_read B(P,kk0) x4
//   4. vmcnt(12): drains aC8          (cover: issued 1 tile ago)
//   5. lgkm(0); 32 MFMA (aC x bS)
//   6. load aC <- A(t+1,kk0)          FIFO [G4,aN8,aC8] = 20
//   7. ds_read B(P,kk1) x4
//   8. vmcnt(8): drains G4+aN8        (cover: ~1 half each)
//   9. lgkm(0); 32 MFMA (aN x bS)
//  10. BAR (buf P^1 complete by 8)    next tile: [aC8]  invariant ok
// ---------------------------------------------------------------------------
#define BK 64
#define NT 64

#define PANEL_B(b,kk) (ldsb + ((b)*2+(kk))*16384)

#define GLL(src, dst) __builtin_amdgcn_global_load_lds( \
    (const __attribute__((address_space(1))) void*)(src), \
    (__attribute__((address_space(3))) void*)(dst), 16, 0, 0)

#define STAGE_B(b, kk, ko) do { \
    GLL(sB1 + (ko) + (kk)*32,          PANEL_B(b,kk) + d1); \
    GLL(sB1 + 524288 + (ko) + (kk)*32, PANEL_B(b,kk) + d1 + 8192); } while(0)

#define SB0  __builtin_amdgcn_sched_barrier(0)
#define BAR  __builtin_amdgcn_s_barrier()
#define PRI1 __builtin_amdgcn_s_setprio(1)
#define PRI0 __builtin_amdgcn_s_setprio(0)
#define WLG0  asm volatile("s_waitcnt lgkmcnt(0)" ::: "memory")
#define WVM12 asm volatile("s_waitcnt vmcnt(12)" ::: "memory")
#define WVM8  asm volatile("s_waitcnt vmcnt(8)" ::: "memory")
#define WVM0  asm volatile("s_waitcnt vmcnt(0)" ::: "memory")

#define LDA8(dst, OFS) do { _Pragma("unroll") \
    for (int m_ = 0; m_ < 8; ++m_) \
        dst[m_] = *(const bf16x8*)(xbh + (OFS) + aoff[m_]); } while (0)

#define LDB4(P, KK) do { _Pragma("unroll") \
    for (int n_ = 0; n_ < 4; ++n_) \
        bS[n_] = *(const bf16x8*)(bB + (P)*32768 + (KK)*16384 + n_*1024); } while (0)

#define MM32(AS) do { _Pragma("unroll") \
    for (int m_ = 0; m_ < 8; ++m_) { _Pragma("unroll") \
    for (int n_ = 0; n_ < 4; ++n_) \
        acc[m_][n_] = __builtin_amdgcn_mfma_f32_16x16x32_bf16( \
            AS[m_], bS[n_], acc[m_][n_], 0, 0, 0); } } while (0)

#define TILEF(P, KO, PF) do { \
    if (PF) { STAGE_B((P)^1, 0, KO); STAGE_B((P)^1, 1, KO); } \
    LDA8(aN, 32); \
    SB0; \
    LDB4(P, 0); \
    SB0; \
    if (PF) { WVM12; } else { WVM8; } \
    WLG0; SB0; \
    PRI1; MM32(aC); PRI0; SB0; \
    if (PF) LDA8(aC, 64); \
    SB0; \
    LDB4(P, 1); \
    SB0; \
    if (PF) { WVM8; } else { WVM0; } \
    WLG0; SB0; \
    PRI1; MM32(aN); PRI0; SB0; \
    BAR; SB0; \
    xbh += 64; \
} while (0)

__global__ __launch_bounds__(512, 2) void gemm_ad_kernel(
    const unsigned short* __restrict__ xb,   // bf16 x [M_ROWS][IN_F]
    const unsigned short* __restrict__ wb,   // bf16 W [OUT_F][IN_F]
    const float* __restrict__ bias,
    float* __restrict__ out)
{
    __shared__ unsigned short lds_us[32768];   // 64 KiB (B only)
    char* const ldsb = (char*)lds_us;

    const int t    = threadIdx.x;
    const int wave = t >> 6;
    const int lane = t & 63;
    const int lr   = lane & 15;
    const int kq   = lane >> 4;
    const int wr   = wave >> 2;      // 0..1  (M)
    const int wcn  = wave & 3;       // 0..3  (N)
    const int sx   = (lr & 6) << 3;

    // XCD-chunked swizzle; bn-major within chunk keeps the A slice L2-hot.
    const int bid  = blockIdx.x;
    const int swzb = (bid & 7) * 128 + (bid >> 3);
    const int bm   = (swzb >> 4) * 256;   // 64 M-tiles
    const int bn   = (swzb & 15) * 256;   // 16 N-tiles

    // B staging: thread t covers 16B chunks t, t+512 of each panel (linear)
    const int r1 = t >> 2;                                // panel row (0..127)
    const int q1 = ((t & 3) * 16) ^ ((r1 & 6) << 3);      // inv-swizzled src byte
    const unsigned short* sB1 = wb + (size_t)(bn + r1) * IN_F + (q1 >> 1);
    const int d1 = t * 16;

    // B read base (swizzled)
    const char* bB = ldsb + (wcn * 64 + lr) * 64 + ((kq * 16) ^ sx);

    // A direct: uniform advancing base + per-lane 32-bit element offsets
    const unsigned short* xbh = xb;
    int aoff[8];
    #pragma unroll
    for (int m = 0; m < 8; ++m)
        aoff[m] = (bm + wr * 128 + m * 16 + lr) * IN_F + kq * 8;

    f32x4 acc[8][4] = {};
    bf16x8 aC[8], aN[8], bS[4];

    // prologue: stage B tile 0 (G4), load aC = A(t0,kk0); drain G4; sync.
    STAGE_B(0, 0, 0); STAGE_B(0, 1, 0);
    LDA8(aC, 0);
    SB0; WVM8; BAR; SB0;
    // entering loop: FIFO = [aC8]  (invariant)

    #pragma unroll 1
    for (int tt = 0; tt < NT - 2; tt += 2) {
        TILEF(0, (tt + 1) * BK, true);
        TILEF(1, (tt + 2) * BK, true);
    }
    TILEF(0, (NT - 1) * BK, true);   // tile 62, stages tile 63's B
    TILEF(1, 0, false);              // tile 63

    // ---- epilogue: C/D layout col=lr, row=kq*4+j ----
    #pragma unroll
    for (int n = 0; n < 4; ++n) {
        const int col = bn + wcn * 64 + n * 16 + lr;
        const float bv = bias[col];
        #pragma unroll
        for (int m = 0; m < 8; ++m) {
            const size_t rb = (size_t)(bm + wr * 128 + m * 16 + kq * 4) * OUT_F + col;
            #pragma unroll
            for (int j = 0; j < 4; ++j)
                out[rb + (size_t)j * OUT_F] = acc[m][n][j] + bv;
        }
    }
}

// ---------------------------------------------------------------------------
// Fallback GEMM (round-1 structure) for small workspace.
// ---------------------------------------------------------------------------
#define FBM 128
#define FBN 128
#define FBK 32

__global__ __launch_bounds__(256) void gemm_fb_kernel(
    const float* __restrict__ xf,
    const unsigned short* __restrict__ wb,
    const float* __restrict__ bias,
    float* __restrict__ out)
{
    __shared__ unsigned short As[FBM * FBK];
    __shared__ unsigned short Bs[FBN * FBK];

    const int t    = threadIdx.x;
    const int wave = t >> 6;
    const int lane = t & 63;
    const int lr   = lane & 15;
    const int kq   = lane >> 4;
    const int wr   = wave >> 1;
    const int wc   = wave & 1;

    const int bm = blockIdx.x * FBM;
    const int bn = blockIdx.y * FBN;
    const int srow = t >> 2;
    const int scol = (t & 3) * 8;

    f32x4 acc[4][4] = {};

    for (int kt = 0; kt < IN_F; kt += FBK) {
        #pragma unroll
        for (int g = 0; g < 2; ++g) {
            const int row = srow + g * 64;
            const float4* xp = (const float4*)(xf + (size_t)(bm + row) * IN_F + kt + scol);
            const float4 a0 = xp[0], a1 = xp[1];
            const float v[8] = {a0.x, a0.y, a0.z, a0.w, a1.x, a1.y, a1.z, a1.w};
            unsigned int pk[4];
            #pragma unroll
            for (int j = 0; j < 4; ++j)
                pk[j] = (unsigned int)f2bf(v[2*j]) | ((unsigned int)f2bf(v[2*j+1]) << 16);
            *reinterpret_cast<uint4*>(&As[row * FBK + scol]) =
                make_uint4(pk[0], pk[1], pk[2], pk[3]);
        }
        {
            const unsigned short* gb0 = wb + (size_t)(bn + srow) * IN_F + kt + scol;
            const unsigned short* gb1 = gb0 + (size_t)64 * IN_F;
            GLL(gb0, Bs + srow * FBK + scol);
            GLL(gb1, Bs + (64 + srow) * FBK + scol);
        }
        __syncthreads();

        bf16x8 af[4], bfr[4];
        #pragma unroll
        for (int m = 0; m < 4; ++m)
            af[m] = *reinterpret_cast<const bf16x8*>(As + (wr * 64 + m * 16 + lr) * FBK + kq * 8);
        #pragma unroll
        for (int n = 0; n < 4; ++n)
            bfr[n] = *reinterpret_cast<const bf16x8*>(Bs + (wc * 64 + n * 16 + lr) * FBK + kq * 8);

        #pragma unroll
        for (int m = 0; m < 4; ++m)
            #pragma unroll
            for (int n = 0; n < 4; ++n)
                acc[m][n] = __builtin_amdgcn_mfma_f32_16x16x32_bf16(af[m], bfr[n], acc[m][n], 0, 0, 0);

        __syncthreads();
    }

    const int crow0 = kq * 4;
    #pragma unroll
    for (int n = 0; n < 4; ++n) {
        const int col = bn + wc * 64 + n * 16 + lr;
        const float bv = bias[col];
        #pragma unroll
        for (int m = 0; m < 4; ++m) {
            const int rowb = bm + wr * 64 + m * 16 + crow0;
            #pragma unroll
            for (int j = 0; j < 4; ++j)
                out[(size_t)(rowb + j) * OUT_F + col] = acc[m][n][j] + bv;
        }
    }
}

// ---------------------------------------------------------------------------
extern "C" void kernel_launch(void* const* d_in, const int* in_sizes, int n_in,
                              void* d_out, int out_size, void* d_ws, size_t ws_size,
                              hipStream_t stream) {
    const float* x      = (const float*)d_in[0];
    const float* weight = (const float*)d_in[1];
    const float* bias   = (const float*)d_in[2];
    const float* leafs  = (const float*)d_in[3];
    float* out = (float*)d_out;

    unsigned short* wb = (unsigned short*)d_ws;
    unsigned short* xbuf = (unsigned short*)((char*)d_ws +
                           (size_t)OUT_F * IN_F * sizeof(unsigned short));

    const size_t need_full = (size_t)OUT_F * IN_F * 2 + (size_t)M_ROWS * IN_F * 2;
    const bool full = ws_size >= need_full;

    if (full) {
        prep_kernel<<<dim3(PREP_NBLK), dim3(256), 0, stream>>>(
            weight, leafs, x, wb, xbuf);
        gemm_ad_kernel<<<dim3((M_ROWS / 256) * (OUT_F / 256)), dim3(512), 0, stream>>>(
            xbuf, wb, bias, out);
    } else {
        prep_kernel<<<dim3(PREP_WBLK), dim3(256), 0, stream>>>(
            weight, leafs, x, wb, xbuf);
        gemm_fb_kernel<<<dim3(M_ROWS / FBM, OUT_F / FBN), dim3(256), 0, stream>>>(
            x, wb, bias, out);
    }
}

// Round 11
// 588.687 us; speedup vs baseline: 2.1562x; 2.1562x over previous
//
#include <hip/hip_runtime.h>
#include <hip/hip_bf16.h>
#include <stdint.h>

typedef __attribute__((ext_vector_type(8))) __bf16 bf16x8;
typedef __attribute__((ext_vector_type(4))) float f32x4;

#define IN_F   4096
#define OUT_F  4096
#define M_ROWS 16384   // 8 * 2048

static __device__ __forceinline__ unsigned short f2bf(float f) {
    unsigned int u = __float_as_uint(f);
    u += 0x7FFFu + ((u >> 16) & 1u);   // round-to-nearest-even
    return (unsigned short)(u >> 16);
}

// ---------------------------------------------------------------------------
// Kernel 1: fused prep.
//   blocks [0, WBLK): build full weight (OUT_F x IN_F) bf16 into wb
//   blocks [WBLK, NBLK): convert x fp32 -> bf16 into xbuf
// ---------------------------------------------------------------------------
#define PREP_WBLK 1366
#define PREP_NBLK 4096

__global__ __launch_bounds__(256) void prep_kernel(
    const float* __restrict__ weight, const float* __restrict__ leafs,
    const float* __restrict__ x,
    unsigned short* __restrict__ wb, unsigned short* __restrict__ xbuf)
{
    const int t = threadIdx.x;
    if (blockIdx.x < PREP_WBLK) {
        __shared__ float s[4][8][8];
        {
            const int o = t >> 6, a = (t >> 3) & 7, b = t & 7;
            float acc = 0.f;
            #pragma unroll
            for (int r = 0; r < 8; ++r)
                acc += leafs[o * 512 + r * 64 + a * 8 + b];
            s[o][a][b] = acc;
        }
        __syncthreads();

        const int total = (OUT_F * IN_F) / 8;
        for (int idx = blockIdx.x * 256 + t; idx < total; idx += PREP_WBLK * 256) {
            const int n  = idx >> 9;
            const int kg = idx & 511;
            const int n0 = n >> 9, n1 = (n >> 6) & 7, n2 = (n >> 3) & 7, n3 = n & 7;
            const int k0 = kg >> 6, k1 = (kg >> 3) & 7, k2 = kg & 7;
            const float p = s[0][k0][n0] * s[1][k1][n1] * s[2][k2][n2];
            const float4* wp = (const float4*)(weight + (size_t)n * IN_F + kg * 8);
            const float4 w0 = wp[0], w1 = wp[1];
            const float wv[8] = {w0.x, w0.y, w0.z, w0.w, w1.x, w1.y, w1.z, w1.w};
            unsigned int pk[4];
            #pragma unroll
            for (int j = 0; j < 4; ++j) {
                unsigned int lo = f2bf(wv[2*j]   + p * s[3][2*j]  [n3]);
                unsigned int hi = f2bf(wv[2*j+1] + p * s[3][2*j+1][n3]);
                pk[j] = lo | (hi << 16);
            }
            *reinterpret_cast<uint4*>(wb + (size_t)n * IN_F + kg * 8) =
                make_uint4(pk[0], pk[1], pk[2], pk[3]);
        }
    } else {
        const long long n8 = (long long)M_ROWS * IN_F / 8;
        const int xblocks = PREP_NBLK - PREP_WBLK;
        for (long long idx = (long long)(blockIdx.x - PREP_WBLK) * 256 + t;
             idx < n8; idx += (long long)xblocks * 256) {
            const float4* xp = (const float4*)(x + idx * 8);
            const float4 a = xp[0], b = xp[1];
            const float v[8] = {a.x, a.y, a.z, a.w, b.x, b.y, b.z, b.w};
            unsigned int pk[4];
            #pragma unroll
            for (int j = 0; j < 4; ++j)
                pk[j] = (unsigned int)f2bf(v[2*j]) | ((unsigned int)f2bf(v[2*j+1]) << 16);
            *reinterpret_cast<uint4*>(xbuf + idx * 8) =
                make_uint4(pk[0], pk[1], pk[2], pk[3]);
        }
    }
}

// ---------------------------------------------------------------------------
// Kernel 2: R3 GEMM (session best: 493 us, MfmaUtil 51.5%, 0 conflicts).
// 256x256 tile, BK=64, 16x16x32 MFMA, 8 waves (2M x 4N), wave tile 128x64.
// LDS panels: A [2buf][2kk][256][64B] at 0, B same at 65536 (panel 16KB).
// Element (row,col): byte row*64 + ((col*2) ^ ((row&6)<<3)).
// Schedule per phase: issue next-subtile ds_reads + this phase's GLLs,
// wait only for the PREVIOUS phase's reads (counted lgkm 4/8/4/8), 16 MFMA,
// [vmcnt(2)] at ph0/ph2 ends, barrier.
// ---------------------------------------------------------------------------
#define BK 64
#define NT 64

#define PANEL_A(b,kk) (ldsb + ((b)*2+(kk))*16384)
#define PANEL_B(b,kk) (ldsb + 65536 + ((b)*2+(kk))*16384)

#define GLL(src, dst) __builtin_amdgcn_global_load_lds( \
    (const __attribute__((address_space(1))) void*)(src), \
    (__attribute__((address_space(3))) void*)(dst), 16, 0, 0)

#define STAGE_A(b, kk, ko) do { \
    GLL(sA1 + (ko) + (kk)*32,          PANEL_A(b,kk) + d1); \
    GLL(sA1 + 524288 + (ko) + (kk)*32, PANEL_A(b,kk) + d1 + 8192); } while(0)
#define STAGE_B(b, kk, ko) do { \
    GLL(sB1 + (ko) + (kk)*32,          PANEL_B(b,kk) + d1); \
    GLL(sB1 + 524288 + (ko) + (kk)*32, PANEL_B(b,kk) + d1 + 8192); } while(0)

#define SB0  __builtin_amdgcn_sched_barrier(0)
#define BAR  __builtin_amdgcn_s_barrier()
#define PRI1 __builtin_amdgcn_s_setprio(1)
#define PRI0 __builtin_amdgcn_s_setprio(0)
#define WLG4 asm volatile("s_waitcnt lgkmcnt(4)" ::: "memory")
#define WLG0 asm volatile("s_waitcnt lgkmcnt(0)" ::: "memory")
#define WVM2 asm volatile("s_waitcnt vmcnt(2)" ::: "memory")
#define WVM0 asm volatile("s_waitcnt vmcnt(0)" ::: "memory")

#define LDA(dst, BUF, KK, MH) do { _Pragma("unroll") \
    for (int i_ = 0; i_ < 4; ++i_) \
        dst[i_] = *(const bf16x8*)(aB + ((BUF)*32768 + (KK)*16384 + ((MH)*4+i_)*1024)); } while(0)
#define LDB(dst, BUF, KK) do { _Pragma("unroll") \
    for (int i_ = 0; i_ < 4; ++i_) \
        dst[i_] = *(const bf16x8*)(bB + ((BUF)*32768 + (KK)*16384 + i_*1024)); } while(0)
#define MM(AS, MH) do { _Pragma("unroll") \
    for (int m_ = 0; m_ < 4; ++m_) { _Pragma("unroll") \
    for (int n_ = 0; n_ < 4; ++n_) \
        acc[(MH)*4+m_][n_] = __builtin_amdgcn_mfma_f32_16x16x32_bf16( \
            AS[m_], bF[n_], acc[(MH)*4+m_][n_], 0, 0, 0); } } while(0)

#define TILE(BUF, KO, PF) do { \
    /* phase 0: MFMA subtile (m0-3,k0); load bF(k0), aQ(m4-7,k0) */ \
    LDB(bF, BUF, 0); \
    LDA(aQ, BUF, 0, 1); \
    if (PF) STAGE_A((BUF)^1, 0, KO); \
    SB0; WLG4; SB0; \
    PRI1; MM(aP, 0); PRI0; SB0; \
    if (PF) { WVM2; } else { WVM0; } \
    BAR; SB0; \
    /* phase 1: MFMA (m4-7,k0); prefetch aP(m0-3,k1) */ \
    LDA(aP, BUF, 1, 0); \
    if (PF) STAGE_B((BUF)^1, 0, KO); \
    SB0; WLG4; SB0; \
    PRI1; MM(aQ, 1); PRI0; SB0; \
    BAR; SB0; \
    /* phase 2: MFMA (m0-3,k1); load bF(k1), aQ(m4-7,k1) */ \
    LDB(bF, BUF, 1); \
    LDA(aQ, BUF, 1, 1); \
    if (PF) STAGE_A((BUF)^1, 1, KO); \
    SB0; WLG4; SB0; \
    PRI1; MM(aP, 0); PRI0; SB0; \
    if (PF) { WVM2; } else { WVM0; } \
    BAR; SB0; \
    /* phase 3: MFMA (m4-7,k1); prefetch aP(m0-3,k0) of NEXT tile */ \
    if (PF) { LDA(aP, (BUF)^1, 0, 0); STAGE_B((BUF)^1, 1, KO); SB0; WLG4; } \
    else    { SB0; WLG0; } \
    SB0; \
    PRI1; MM(aQ, 1); PRI0; SB0; \
    BAR; SB0; \
} while (0)

__global__ __launch_bounds__(512, 2) void gemm8_kernel(
    const unsigned short* __restrict__ xb,   // bf16 x [M_ROWS][IN_F]
    const unsigned short* __restrict__ wb,   // bf16 W [OUT_F][IN_F]
    const float* __restrict__ bias,
    float* __restrict__ out)
{
    __shared__ unsigned short lds_us[65536];   // 128 KiB
    char* const ldsb = (char*)lds_us;

    const int t    = threadIdx.x;
    const int wave = t >> 6;
    const int lane = t & 63;
    const int lr   = lane & 15;
    const int kq   = lane >> 4;
    const int wr   = wave >> 2;      // 0..1  (M)
    const int wcn  = wave & 3;       // 0..3  (N)
    const int sx   = (lr & 6) << 3;

    // XCD-chunked swizzle; within an XCD chunk: bn-major so the A slice
    // stays L2-hot while B streams.
    const int bid  = blockIdx.x;
    const int swzb = (bid & 7) * 128 + (bid >> 3);
    const int bm   = (swzb >> 4) * 256;   // 64 M-tiles
    const int bn   = (swzb & 15) * 256;   // 16 N-tiles

    // staging: thread t covers 16B chunks t and t+512 of each panel (linear)
    const int c1 = t;
    const int r1 = c1 >> 2;                               // panel row (0..127)
    const int q1 = ((c1 & 3) * 16) ^ ((r1 & 6) << 3);     // inv-swizzled src byte
    const unsigned short* sA1 = xb + (size_t)(bm + r1) * IN_F + (q1 >> 1);
    const unsigned short* sB1 = wb + (size_t)(bn + r1) * IN_F + (q1 >> 1);
    const int d1 = c1 * 16;                               // lds dest (linear)
    // chunk 2: row r1+128 (same swizzle since (r+128)&6 == r&6), global
    // +128 rows = +524288 elements, lds dest d1 + 8192.

    // per-lane read bases (swizzled); fragment offsets are immediates
    const char* aB = ldsb + (wr * 128 + lr) * 64 + ((kq * 16) ^ sx);
    const char* bB = ldsb + 65536 + (wcn * 64 + lr) * 64 + ((kq * 16) ^ sx);

    f32x4 acc[8][4] = {};
    bf16x8 aP[4], aQ[4], bF[4];

    // prologue: stage tile 0 panels (FIFO: A-k0, B-k0, A-k1, B-k1), drain k0,
    // barrier, preload ph0's A regs. Entering ph0: vm outstanding = 4 (k1
    // panels), lgkm outstanding = 4 (aP reads).
    STAGE_A(0, 0, 0); STAGE_B(0, 0, 0); STAGE_A(0, 1, 0); STAGE_B(0, 1, 0);
    asm volatile("s_waitcnt vmcnt(4)" ::: "memory");
    BAR; SB0;
    LDA(aP, 0, 0, 0);

    #pragma unroll 1
    for (int tt = 0; tt < NT - 2; tt += 2) {
        const int ko0 = (tt + 1) * BK;
        const int ko1 = (tt + 2) * BK;
        TILE(0, ko0, true);
        TILE(1, ko1, true);
    }
    TILE(0, (NT - 1) * BK, true);   // tile 62, stages tile 63
    TILE(1, 0, false);              // tile 63, no staging, conservative waits

    // ---- epilogue: C/D layout col=lr, row=kq*4+j ----
    #pragma unroll
    for (int n = 0; n < 4; ++n) {
        const int col = bn + wcn * 64 + n * 16 + lr;
        const float bv = bias[col];
        #pragma unroll
        for (int m = 0; m < 8; ++m) {
            const size_t rb = (size_t)(bm + wr * 128 + m * 16 + kq * 4) * OUT_F + col;
            #pragma unroll
            for (int j = 0; j < 4; ++j)
                out[rb + (size_t)j * OUT_F] = acc[m][n][j] + bv;
        }
    }
}

// ---------------------------------------------------------------------------
// Fallback GEMM (round-1 structure) for small workspace.
// ---------------------------------------------------------------------------
#define FBM 128
#define FBN 128
#define FBK 32

__global__ __launch_bounds__(256) void gemm_fb_kernel(
    const float* __restrict__ xf,
    const unsigned short* __restrict__ wb,
    const float* __restrict__ bias,
    float* __restrict__ out)
{
    __shared__ unsigned short As[FBM * FBK];
    __shared__ unsigned short Bs[FBN * FBK];

    const int t    = threadIdx.x;
    const int wave = t >> 6;
    const int lane = t & 63;
    const int lr   = lane & 15;
    const int kq   = lane >> 4;
    const int wr   = wave >> 1;
    const int wc   = wave & 1;

    const int bm = blockIdx.x * FBM;
    const int bn = blockIdx.y * FBN;
    const int srow = t >> 2;
    const int scol = (t & 3) * 8;

    f32x4 acc[4][4] = {};

    for (int kt = 0; kt < IN_F; kt += FBK) {
        #pragma unroll
        for (int g = 0; g < 2; ++g) {
            const int row = srow + g * 64;
            const float4* xp = (const float4*)(xf + (size_t)(bm + row) * IN_F + kt + scol);
            const float4 a0 = xp[0], a1 = xp[1];
            const float v[8] = {a0.x, a0.y, a0.z, a0.w, a1.x, a1.y, a1.z, a1.w};
            unsigned int pk[4];
            #pragma unroll
            for (int j = 0; j < 4; ++j)
                pk[j] = (unsigned int)f2bf(v[2*j]) | ((unsigned int)f2bf(v[2*j+1]) << 16);
            *reinterpret_cast<uint4*>(&As[row * FBK + scol]) =
                make_uint4(pk[0], pk[1], pk[2], pk[3]);
        }
        {
            const unsigned short* gb0 = wb + (size_t)(bn + srow) * IN_F + kt + scol;
            const unsigned short* gb1 = gb0 + (size_t)64 * IN_F;
            GLL(gb0, Bs + srow * FBK + scol);
            GLL(gb1, Bs + (64 + srow) * FBK + scol);
        }
        __syncthreads();

        bf16x8 af[4], bfr[4];
        #pragma unroll
        for (int m = 0; m < 4; ++m)
            af[m] = *reinterpret_cast<const bf16x8*>(As + (wr * 64 + m * 16 + lr) * FBK + kq * 8);
        #pragma unroll
        for (int n = 0; n < 4; ++n)
            bfr[n] = *reinterpret_cast<const bf16x8*>(Bs + (wc * 64 + n * 16 + lr) * FBK + kq * 8);

        #pragma unroll
        for (int m = 0; m < 4; ++m)
            #pragma unroll
            for (int n = 0; n < 4; ++n)
                acc[m][n] = __builtin_amdgcn_mfma_f32_16x16x32_bf16(af[m], bfr[n], acc[m][n], 0, 0, 0);

        __syncthreads();
    }

    const int crow0 = kq * 4;
    #pragma unroll
    for (int n = 0; n < 4; ++n) {
        const int col = bn + wc * 64 + n * 16 + lr;
        const float bv = bias[col];
        #pragma unroll
        for (int m = 0; m < 4; ++m) {
            const int rowb = bm + wr * 64 + m * 16 + crow0;
            #pragma unroll
            for (int j = 0; j < 4; ++j)
                out[(size_t)(rowb + j) * OUT_F + col] = acc[m][n][j] + bv;
        }
    }
}

// ---------------------------------------------------------------------------
extern "C" void kernel_launch(void* const* d_in, const int* in_sizes, int n_in,
                              void* d_out, int out_size, void* d_ws, size_t ws_size,
                              hipStream_t stream) {
    const float* x      = (const float*)d_in[0];
    const float* weight = (const float*)d_in[1];
    const float* bias   = (const float*)d_in[2];
    const float* leafs  = (const float*)d_in[3];
    float* out = (float*)d_out;

    unsigned short* wb = (unsigned short*)d_ws;
    unsigned short* xbuf = (unsigned short*)((char*)d_ws +
                           (size_t)OUT_F * IN_F * sizeof(unsigned short));

    const size_t need_full = (size_t)OUT_F * IN_F * 2 + (size_t)M_ROWS * IN_F * 2;
    const bool full = ws_size >= need_full;

    if (full) {
        prep_kernel<<<dim3(PREP_NBLK), dim3(256), 0, stream>>>(
            weight, leafs, x, wb, xbuf);
        gemm8_kernel<<<dim3((M_ROWS / 256) * (OUT_F / 256)), dim3(512), 0, stream>>>(
            xbuf, wb, bias, out);
    } else {
        prep_kernel<<<dim3(PREP_WBLK), dim3(256), 0, stream>>>(
            weight, leafs, x, wb, xbuf);
        gemm_fb_kernel<<<dim3(M_ROWS / FBM, OUT_F / FBN), dim3(256), 0, stream>>>(
            x, wb, bias, out);
    }
}